// Round 20
// baseline (132.480 us; speedup 1.0000x reference)
//
#include <hip/hip_runtime.h>
#include <hip/hip_bf16.h>
#include <math.h>

#define NR 8
#define NB 8
#define NH 32
#define NKVH 8
#define NG 4
#define ND 128
#define NDV 128
#define NPAGE 2048
#define KSTR (NKVH*ND)        // 1024 floats per page (all kvh slices)
#define NCH 16                // chunks per rank
#define CHUNK 128             // pages per block
#define NT 4                  // tiles per block
#define NROW (NB*NKVH*NG)     // 256 output rows
#define QSCALE 0.088388347648318447f

typedef __attribute__((ext_vector_type(8))) short bf16x8;
typedef __attribute__((ext_vector_type(4))) float f32x4;

static __device__ __forceinline__ short f2bf(float x) {
  __hip_bfloat16 h = __float2bfloat16(x);
  return __builtin_bit_cast(short, h);
}

// async global->LDS, 16B per lane; LDS dest = wave-uniform base + lane*16
static __device__ __forceinline__ void gload_lds16(const float* g, float* l) {
  __builtin_amdgcn_global_load_lds(
      (__attribute__((address_space(1))) void*)g,
      (__attribute__((address_space(3))) void*)l, 16, 0, 0);
}

// ---------------- histogram: cntf[r][b][pg] = (float) multiplicity
__global__ __launch_bounds__(256) void build_counts(
    const int* __restrict__ kv_lens, const int* __restrict__ bt_all,
    float* __restrict__ cntf) {
  const int rb = blockIdx.x;             // r*NB + b
  __shared__ int h[NPAGE];
  for (int i = threadIdx.x; i < NPAGE; i += 256) h[i] = 0;
  __syncthreads();
  const int len = kv_lens[rb];
  const int* bt = bt_all + (size_t)rb * NPAGE;
  for (int i = threadIdx.x; i < len; i += 256) atomicAdd(&h[bt[i]], 1);
  __syncthreads();
  float* o = cntf + (size_t)rb * NPAGE;
  for (int i = threadIdx.x; i < NPAGE; i += 256) o[i] = (float)h[i];
}

// ---------------- MFMA weighted-stream attention, block-cooperative tiles.
// R20: TRUE min volume + 16 waves/CU. Block = (r,kvh,chunk16): 1024 blocks,
// 4 waves, 4 tiles x 32 block-shared pages. V staged once (block-coop, 16KB);
// K read by the 2 gp-waves of the same page-half -> 2nd read L1-hits (8KB
// tile << 32KB L1): K leaves L2 ONCE. QK role (gp=wid>>1, ph=wid&1); PV role
// (gp=wid>>1, dvh=wid&1) -> disjoint output quadrants, O in 16 VGPR, no LDS
// merge. m=0 softmax => partials are LINEAR: blocks atomicAdd unnormalized
// O/L into a 129KB global accumulator; combine = normalize only.
// LDS 9216 floats = 36,864 B -> 4 blocks/CU, grid 1024 = one round:
//   [0 .. 8192f)   V dbuf: bf*4096 + pg*128 + d
//   [8192..9216f)  P: 8192 + gp*512 + pg*16 + qr
__global__ __launch_bounds__(256, 1) void attn_partial(
    const float* __restrict__ q,
    const float* __restrict__ k_cache,
    const float* __restrict__ v_cache,
    const float* __restrict__ cntf,
    float* __restrict__ O_acc,    // [NROW][NDV] unnormalized sums
    float* __restrict__ L_acc)    // [NROW]
{
  const int bid   = blockIdx.x;
  const int r     = bid & 7;              // XCD pin (bid%8 == XCD)
  const int kvh   = (bid >> 3) & 7;
  const int chunk = bid >> 6;             // 0..15

  const int tid  = threadIdx.x;
  const int wid  = tid >> 6;
  const int lane = tid & 63;
  const int col  = lane & 15;
  const int hq   = lane >> 4;
  const int gp   = wid >> 1;      // g-pair (both roles)
  const int ph   = wid & 1;       // QK: page half
  const int dvh  = wid & 1;       // PV: dv half

  __shared__ float LB[9216];      // 36,864 B -> 4 blocks/CU

  // ---- Q A-frags for OWN g-pair only (bf16, pre-scaled)
  bf16x8 qf[4];
  {
    const int b = col & 7;
    const int g = gp * 2 + (col >> 3);
    const float* qp = q + ((size_t)b * NH + kvh * NG + g) * ND + hq * 8;
#pragma unroll
    for (int st = 0; st < 4; ++st) {
      const float4 t0 = *(const float4*)(qp + st * 32);
      const float4 t1 = *(const float4*)(qp + st * 32 + 4);
      bf16x8 f;
      f[0] = f2bf(t0.x * QSCALE); f[1] = f2bf(t0.y * QSCALE);
      f[2] = f2bf(t0.z * QSCALE); f[3] = f2bf(t0.w * QSCALE);
      f[4] = f2bf(t1.x * QSCALE); f[5] = f2bf(t1.y * QSCALE);
      f[6] = f2bf(t1.z * QSCALE); f[7] = f2bf(t1.w * QSCALE);
      qf[st] = f;
    }
  }

  const int pg0 = chunk * CHUNK;               // block's first page
  const float* Kb = k_cache + (size_t)r * NPAGE * KSTR + kvh * ND;
  const float* Vb = v_cache + (size_t)r * NPAGE * KSTR + kvh * NDV;

  // block-coop V stage: wave wid stages pages [wid*8, wid*8+8) of the tile
#define STAGE_V(bf, t_)                                                      \
  {                                                                          \
    _Pragma("unroll")                                                        \
    for (int i = 0; i < 4; ++i) {                                            \
      const int pgl = wid * 8 + 2 * i + (lane >> 5);                         \
      const float* s_ =                                                      \
          Vb + (size_t)(pg0 + (t_) * 32 + pgl) * KSTR + (lane & 31) * 4;     \
      gload_lds16(s_, &LB[(bf) * 4096 + (wid * 8 + 2 * i) * 128]);           \
    }                                                                        \
  }
  // per-wave K: its 16 pages (page half ph) of the tile
#define KLOAD(dst, t_)                                                       \
  {                                                                          \
    const float* kp_ =                                                       \
        Kb + (size_t)(pg0 + (t_) * 32 + ph * 16 + col) * KSTR + hq * 8;      \
    _Pragma("unroll")                                                        \
    for (int st = 0; st < 4; ++st) {                                         \
      dst[2 * st]     = *(const float4*)(kp_ + st * 32);                     \
      dst[2 * st + 1] = *(const float4*)(kp_ + st * 32 + 4);                 \
    }                                                                        \
  }
#define CWLOAD(dst, t_)                                                      \
  {                                                                          \
    _Pragma("unroll")                                                        \
    for (int rg = 0; rg < 4; ++rg)                                           \
      dst[rg] = cntf[((size_t)(r * NB + ((hq * 4 + rg) & 7))) * NPAGE +      \
                     pg0 + (t_) * 32 + ph * 16 + col];                       \
  }

  float4 kr[2][8];
  float  cwl[2][4];

  // prologue: stage tile 0 (V before K so kr auto-wait drains V too)
  STAGE_V(0, 0);
  KLOAD(kr[0], 0);
  CWLOAD(cwl[0], 0);

  float l[4] = {0.f, 0.f, 0.f, 0.f};
  f32x4 O[4];                    // row hq*4+rg, dims dvh*64 + col*4..+3
#pragma unroll
  for (int rg = 0; rg < 4; ++rg) O[rg] = (f32x4){0.f, 0.f, 0.f, 0.f};

#pragma unroll
  for (int t = 0; t < NT; ++t) {
    const int bf = t & 1;

    // ---- QK^T: 4 MFMAs, own gp (kr auto-wait also drains own V(t) stages)
    f32x4 acc = (f32x4){0.f, 0.f, 0.f, 0.f};
#pragma unroll
    for (int st = 0; st < 4; ++st) {
      const float4 a0 = kr[bf][2 * st];
      const float4 a1 = kr[bf][2 * st + 1];
      bf16x8 kf;
      kf[0] = f2bf(a0.x); kf[1] = f2bf(a0.y); kf[2] = f2bf(a0.z); kf[3] = f2bf(a0.w);
      kf[4] = f2bf(a1.x); kf[5] = f2bf(a1.y); kf[6] = f2bf(a1.z); kf[7] = f2bf(a1.w);
      acc = __builtin_amdgcn_mfma_f32_16x16x32_bf16(qf[st], kf, acc, 0, 0, 0);
    }

    // ---- shuffle-free weighted softmax terms (fixed shift m=0)
    float p[4];
#pragma unroll
    for (int rg = 0; rg < 4; ++rg) {
      p[rg] = cwl[bf][rg] * __expf(acc[rg]);
      l[rg] += p[rg];
    }
    *(f32x4*)&LB[8192 + gp * 512 + (ph * 16 + col) * 16 + hq * 4] =
        (f32x4){p[0], p[1], p[2], p[3]};

    // ---- prefetch tile t+1 (V into bf^1: PV(t-1) readers passed barrier#2)
    if (t < NT - 1) {
      STAGE_V(bf ^ 1, t + 1);
      KLOAD(kr[bf ^ 1], t + 1);
      CWLOAD(cwl[bf ^ 1], t + 1);
    }
    __syncthreads();                     // P(t) visible; all waves' V(t) done

    // ---- PV: own (gp, dvh) quadrant over all 32 pages
#pragma unroll 4
    for (int pg = 0; pg < 32; ++pg) {
      const f32x4 pw = *(const f32x4*)&LB[8192 + gp * 512 + pg * 16 + hq * 4];
      const f32x4 va = *(const f32x4*)&LB[bf * 4096 + pg * 128 + dvh * 64 + col * 4];
#pragma unroll
      for (int rg = 0; rg < 4; ++rg) O[rg] += pw[rg] * va;
    }
    __syncthreads();                     // PV done: P/V(bf) reusable
  }

  // ---- L: butterfly over the 16 page-lanes, atomicAdd (both ph waves add)
#pragma unroll
  for (int mk = 1; mk <= 8; mk <<= 1)
#pragma unroll
    for (int rg = 0; rg < 4; ++rg) l[rg] += __shfl_xor(l[rg], mk);
  if (col == 0) {
#pragma unroll
    for (int rg = 0; rg < 4; ++rg) {
      const int qr = hq * 4 + rg;
      const int row = (((qr & 7) * NKVH + kvh) * NG) + gp * 2 + (qr >> 3);
      atomicAdd(&L_acc[row], l[rg]);
    }
  }

  // ---- O: own quadrant, atomicAdd unnormalized sums
#pragma unroll
  for (int rg = 0; rg < 4; ++rg) {
    const int qr = hq * 4 + rg;
    const int row = (((qr & 7) * NKVH + kvh) * NG) + gp * 2 + (qr >> 3);
    float* dst = O_acc + (size_t)row * NDV + dvh * 64 + col * 4;
    atomicAdd(dst + 0, O[rg].x);
    atomicAdd(dst + 1, O[rg].y);
    atomicAdd(dst + 2, O[rg].z);
    atomicAdd(dst + 3, O[rg].w);
  }
}

// ---------------- normalize: out = O_acc / L_acc
__global__ __launch_bounds__(128) void attn_combine(
    const float* __restrict__ O_acc,
    const float* __restrict__ L_acc,
    float* __restrict__ out)
{
  const int row = blockIdx.x;
  const int d   = threadIdx.x;
  const float L = L_acc[row];
  const float inv = (L > 0.f) ? 1.f / L : 0.f;
  out[(size_t)row * NDV + d] = O_acc[(size_t)row * NDV + d] * inv;
}

extern "C" void kernel_launch(void* const* d_in, const int* in_sizes, int n_in,
                              void* d_out, int out_size, void* d_ws, size_t ws_size,
                              hipStream_t stream) {
  const float* q        = (const float*)d_in[0];
  const float* k_cache  = (const float*)d_in[1];
  const float* v_cache  = (const float*)d_in[2];
  const int*   kv_lens  = (const int*)d_in[3];
  const int*   bt       = (const int*)d_in[4];
  float* out = (float*)d_out;

  float* O_acc = (float*)d_ws;                     // 128 KB
  float* L_acc = O_acc + (size_t)NROW * NDV;       // 1 KB
  float* cntf  = L_acc + NROW;                     // 512 KB

  hipMemsetAsync(d_ws, 0, (size_t)(NROW * NDV + NROW) * sizeof(float), stream);
  build_counts<<<NR * NB, 256, 0, stream>>>(kv_lens, bt, cntf);
  attn_partial<<<NR * NKVH * NCH, 256, 0, stream>>>(
      q, k_cache, v_cache, cntf, O_acc, L_acc);
  attn_combine<<<NROW, NDV, 0, stream>>>(O_acc, L_acc, out);
}

// Round 21
// 53.424 us; speedup vs baseline: 2.4798x; 2.4798x over previous
//
#include <hip/hip_runtime.h>
#include <hip/hip_bf16.h>
#include <math.h>

#define NR 8
#define NB 8
#define NH 32
#define NKVH 8
#define NG 4
#define ND 128
#define NDV 128
#define NPAGE 2048
#define KSTR (NKVH*ND)        // 1024 floats per page (all kvh slices)
#define NCH 16                // chunks per rank
#define CHUNK 128             // pages per block
#define NT 4                  // tiles per block (32 pages each)
#define NROW (NB*NKVH*NG)     // 256 output rows
#define NPART (NR*NCH)        // 128 partial slots (r,chunk)
#define QSCALE 0.088388347648318447f

typedef __attribute__((ext_vector_type(8))) short bf16x8;
typedef __attribute__((ext_vector_type(4))) float f32x4;

static __device__ __forceinline__ short f2bf(float x) {
  __hip_bfloat16 h = __float2bfloat16(x);
  return __builtin_bit_cast(short, h);
}

// async global->LDS, 16B per lane; LDS dest = wave-uniform base + lane*16
static __device__ __forceinline__ void gload_lds16(const float* g, float* l) {
  __builtin_amdgcn_global_load_lds(
      (__attribute__((address_space(1))) void*)g,
      (__attribute__((address_space(3))) void*)l, 16, 0, 0);
}

// ---------------- histogram: cntf[r][b][pg] = (float) multiplicity
__global__ __launch_bounds__(256) void build_counts(
    const int* __restrict__ kv_lens, const int* __restrict__ bt_all,
    float* __restrict__ cntf) {
  const int rb = blockIdx.x;             // r*NB + b
  __shared__ int h[NPAGE];
  for (int i = threadIdx.x; i < NPAGE; i += 256) h[i] = 0;
  __syncthreads();
  const int len = kv_lens[rb];
  const int* bt = bt_all + (size_t)rb * NPAGE;
  for (int i = threadIdx.x; i < len; i += 256) atomicAdd(&h[bt[i]], 1);
  __syncthreads();
  float* o = cntf + (size_t)rb * NPAGE;
  for (int i = threadIdx.x; i < NPAGE; i += 256) o[i] = (float)h[i];
}

// ---------------- MFMA weighted-stream attention, block-cooperative tiles.
// R21 = R20 loop (true-min volume + 16 waves/CU) with a PARTIAL-WRITE
// epilogue instead of device-scope atomics (R20's 70us tail).
// Block = (r,kvh,chunk16): 1024 blocks, 4 waves, 4 tiles x 32 shared pages.
// V staged once block-coop; K read by the 2 gp-waves of a page-half -> 2nd
// read L1-hits; QK role (gp,ph), PV role (gp,dvh) -> disjoint quadrants.
// m=0 softmax => partials LINEAR: block writes unnormalized O/L to its
// (r,chunk) slot; combine = plain sums + divide.
// LDS 9216 floats = 36,864 B -> 4 blocks/CU, grid 1024 = one round:
//   [0 .. 8192f)   V dbuf: bf*4096 + pg*128 + d
//   [8192..9216f)  P: 8192 + gp*512 + pg*16 + qr   (l-merge overlays after)
__global__ __launch_bounds__(256, 1) void attn_partial(
    const float* __restrict__ q,
    const float* __restrict__ k_cache,
    const float* __restrict__ v_cache,
    const float* __restrict__ cntf,
    float* __restrict__ ws_o,     // [NPART][NROW][NDV] unnormalized
    float* __restrict__ ws_l)     // [NPART][NROW]
{
  const int bid   = blockIdx.x;
  const int r     = bid & 7;              // XCD pin (bid%8 == XCD)
  const int kvh   = (bid >> 3) & 7;
  const int chunk = bid >> 6;             // 0..15

  const int tid  = threadIdx.x;
  const int wid  = tid >> 6;
  const int lane = tid & 63;
  const int col  = lane & 15;
  const int hq   = lane >> 4;
  const int gp   = wid >> 1;      // g-pair (both roles)
  const int ph   = wid & 1;       // QK: page half
  const int dvh  = wid & 1;       // PV: dv half

  __shared__ float LB[9216];      // 36,864 B -> 4 blocks/CU

  // ---- Q A-frags for OWN g-pair only (bf16, pre-scaled)
  bf16x8 qf[4];
  {
    const int b = col & 7;
    const int g = gp * 2 + (col >> 3);
    const float* qp = q + ((size_t)b * NH + kvh * NG + g) * ND + hq * 8;
#pragma unroll
    for (int st = 0; st < 4; ++st) {
      const float4 t0 = *(const float4*)(qp + st * 32);
      const float4 t1 = *(const float4*)(qp + st * 32 + 4);
      bf16x8 f;
      f[0] = f2bf(t0.x * QSCALE); f[1] = f2bf(t0.y * QSCALE);
      f[2] = f2bf(t0.z * QSCALE); f[3] = f2bf(t0.w * QSCALE);
      f[4] = f2bf(t1.x * QSCALE); f[5] = f2bf(t1.y * QSCALE);
      f[6] = f2bf(t1.z * QSCALE); f[7] = f2bf(t1.w * QSCALE);
      qf[st] = f;
    }
  }

  const int pg0 = chunk * CHUNK;               // block's first page
  const float* Kb = k_cache + (size_t)r * NPAGE * KSTR + kvh * ND;
  const float* Vb = v_cache + (size_t)r * NPAGE * KSTR + kvh * NDV;

  // block-coop V stage: wave wid stages pages [wid*8, wid*8+8) of the tile
#define STAGE_V(bf, t_)                                                      \
  {                                                                          \
    _Pragma("unroll")                                                        \
    for (int i = 0; i < 4; ++i) {                                            \
      const int pgl = wid * 8 + 2 * i + (lane >> 5);                         \
      const float* s_ =                                                      \
          Vb + (size_t)(pg0 + (t_) * 32 + pgl) * KSTR + (lane & 31) * 4;     \
      gload_lds16(s_, &LB[(bf) * 4096 + (wid * 8 + 2 * i) * 128]);           \
    }                                                                        \
  }
  // per-wave K: its 16 pages (page half ph) of the tile
#define KLOAD(dst, t_)                                                       \
  {                                                                          \
    const float* kp_ =                                                       \
        Kb + (size_t)(pg0 + (t_) * 32 + ph * 16 + col) * KSTR + hq * 8;      \
    _Pragma("unroll")                                                        \
    for (int st = 0; st < 4; ++st) {                                         \
      dst[2 * st]     = *(const float4*)(kp_ + st * 32);                     \
      dst[2 * st + 1] = *(const float4*)(kp_ + st * 32 + 4);                 \
    }                                                                        \
  }
#define CWLOAD(dst, t_)                                                      \
  {                                                                          \
    _Pragma("unroll")                                                        \
    for (int rg = 0; rg < 4; ++rg)                                           \
      dst[rg] = cntf[((size_t)(r * NB + ((hq * 4 + rg) & 7))) * NPAGE +      \
                     pg0 + (t_) * 32 + ph * 16 + col];                       \
  }

  float4 kr[2][8];
  float  cwl[2][4];

  // prologue: stage tile 0 (V before K so kr auto-wait drains V too)
  STAGE_V(0, 0);
  KLOAD(kr[0], 0);
  CWLOAD(cwl[0], 0);

  float l[4] = {0.f, 0.f, 0.f, 0.f};
  f32x4 O[4];                    // row hq*4+rg, dims dvh*64 + col*4..+3
#pragma unroll
  for (int rg = 0; rg < 4; ++rg) O[rg] = (f32x4){0.f, 0.f, 0.f, 0.f};

#pragma unroll
  for (int t = 0; t < NT; ++t) {
    const int bf = t & 1;

    // ---- QK^T: 4 MFMAs, own gp
    f32x4 acc = (f32x4){0.f, 0.f, 0.f, 0.f};
#pragma unroll
    for (int st = 0; st < 4; ++st) {
      const float4 a0 = kr[bf][2 * st];
      const float4 a1 = kr[bf][2 * st + 1];
      bf16x8 kf;
      kf[0] = f2bf(a0.x); kf[1] = f2bf(a0.y); kf[2] = f2bf(a0.z); kf[3] = f2bf(a0.w);
      kf[4] = f2bf(a1.x); kf[5] = f2bf(a1.y); kf[6] = f2bf(a1.z); kf[7] = f2bf(a1.w);
      acc = __builtin_amdgcn_mfma_f32_16x16x32_bf16(qf[st], kf, acc, 0, 0, 0);
    }

    // ---- shuffle-free weighted softmax terms (fixed shift m=0)
    float p[4];
#pragma unroll
    for (int rg = 0; rg < 4; ++rg) {
      p[rg] = cwl[bf][rg] * __expf(acc[rg]);
      l[rg] += p[rg];
    }
    *(f32x4*)&LB[8192 + gp * 512 + (ph * 16 + col) * 16 + hq * 4] =
        (f32x4){p[0], p[1], p[2], p[3]};

    // ---- prefetch tile t+1
    if (t < NT - 1) {
      STAGE_V(bf ^ 1, t + 1);
      KLOAD(kr[bf ^ 1], t + 1);
      CWLOAD(cwl[bf ^ 1], t + 1);
    }
    __syncthreads();                     // P(t) visible; all waves' V(t) done

    // ---- PV: own (gp, dvh) quadrant over all 32 pages
#pragma unroll 4
    for (int pg = 0; pg < 32; ++pg) {
      const f32x4 pw = *(const f32x4*)&LB[8192 + gp * 512 + pg * 16 + hq * 4];
      const f32x4 va = *(const f32x4*)&LB[bf * 4096 + pg * 128 + dvh * 64 + col * 4];
#pragma unroll
      for (int rg = 0; rg < 4; ++rg) O[rg] += pw[rg] * va;
    }
    __syncthreads();                     // PV done: P/V(bf) reusable
  }

  // ---- l: butterfly over the 16 page-lanes, stash per (gp,ph) in dead P
#pragma unroll
  for (int mk = 1; mk <= 8; mk <<= 1)
#pragma unroll
    for (int rg = 0; rg < 4; ++rg) l[rg] += __shfl_xor(l[rg], mk);
  if (col == 0) {
#pragma unroll
    for (int rg = 0; rg < 4; ++rg)
      LB[8192 + (gp * 2 + ph) * 16 + hq * 4 + rg] = l[rg];
  }
  __syncthreads();

  // ---- partial write: unnormalized O quadrant + L (slot = (r,chunk))
  const int pi = r * NCH + chunk;
#pragma unroll
  for (int rg = 0; rg < 4; ++rg) {
    const int qr = hq * 4 + rg;
    const int row = (((qr & 7) * NKVH + kvh) * NG) + gp * 2 + (qr >> 3);
    *(float4*)(ws_o + ((size_t)pi * NROW + row) * NDV + dvh * 64 + col * 4) =
        make_float4(O[rg].x, O[rg].y, O[rg].z, O[rg].w);
  }
  if (dvh == 0 && col == 0) {
#pragma unroll
    for (int rg = 0; rg < 4; ++rg) {
      const int qr = hq * 4 + rg;
      const int row = (((qr & 7) * NKVH + kvh) * NG) + gp * 2 + (qr >> 3);
      ws_l[(size_t)pi * NROW + row] =
          LB[8192 + (gp * 2 + 0) * 16 + qr] + LB[8192 + (gp * 2 + 1) * 16 + qr];
    }
  }
}

// ---------------- combine: plain sums over 128 partials (common m=0), divide
__global__ __launch_bounds__(128) void attn_combine(
    const float* __restrict__ ws_o,
    const float* __restrict__ ws_l,
    float* __restrict__ out)
{
  const int row = blockIdx.x;
  const int d   = threadIdx.x;
  float acc = 0.f, L = 0.f;
#pragma unroll 8
  for (int s = 0; s < NPART; ++s) {
    acc += ws_o[((size_t)s * NROW + row) * NDV + d];
    L   += ws_l[(size_t)s * NROW + row];
  }
  out[(size_t)row * NDV + d] = (L > 0.f) ? (acc / L) : 0.f;
}

extern "C" void kernel_launch(void* const* d_in, const int* in_sizes, int n_in,
                              void* d_out, int out_size, void* d_ws, size_t ws_size,
                              hipStream_t stream) {
  const float* q        = (const float*)d_in[0];
  const float* k_cache  = (const float*)d_in[1];
  const float* v_cache  = (const float*)d_in[2];
  const int*   kv_lens  = (const int*)d_in[3];
  const int*   bt       = (const int*)d_in[4];
  float* out = (float*)d_out;

  float* ws_o  = (float*)d_ws;                             // 16.8 MB
  float* ws_l  = ws_o + (size_t)NPART * NROW * NDV;        // 128 KB
  float* cntf  = ws_l + (size_t)NPART * NROW;              // 512 KB

  build_counts<<<NR * NB, 256, 0, stream>>>(kv_lens, bt, cntf);
  attn_partial<<<NR * NKVH * NCH, 256, 0, stream>>>(
      q, k_cache, v_cache, cntf, ws_o, ws_l);
  attn_combine<<<NROW, NDV, 0, stream>>>(ws_o, ws_l, out);
}